// Round 1
// baseline (2614.348 us; speedup 1.0000x reference)
//
#include <hip/hip_runtime.h>
#include <math.h>

// Fused Actor network, fp32 baseline.
// B=65536, NI=376, blending 376->128->128->2(softmax), experts 376->256->128->17 (blended, tanh)
// One block = 64 samples, 512 threads = 8 waves.
// lane (0..63) = sample row, wave (0..7) = output column group -> weight loads wave-uniform.

#define NI   376
#define MT   64
#define T    512
#define SSP  377   // states LDS row stride (377 mod 32 = 25, odd -> conflict-free)
#define G1P  129
#define H1P  257
#define H2P  129

// LDS float layout:
//  Ss  [0, 24128)            : states [64][377]   (live: load..phase B)
//  G1  [24128, 32384)        : g1 [64][129]       (live: A1..A2)
//  G2  [32384, 40640)        : g2 [64][129]       (live: A2..A3)
//  CF  [40640, 40768)        : coeffs [64][2]     (live: A3..D)
//  H1 = [24128, 40576)       : h1 [64][257]       (overlays G1+G2, live: B..C)
//  H2 = [0, 8256)            : h2 [64][129]       (overlays Ss,    live: C..D)
#define LDS_FLOATS 40768

__global__ __launch_bounds__(512, 2)
void actor_kernel(const float* __restrict__ states,
                  const float* __restrict__ bw1, const float* __restrict__ bb1,
                  const float* __restrict__ bw2, const float* __restrict__ bb2,
                  const float* __restrict__ bwo, const float* __restrict__ bbo,
                  const float* __restrict__ ew1, const float* __restrict__ eb1,
                  const float* __restrict__ ew2, const float* __restrict__ eb2,
                  const float* __restrict__ ewm, const float* __restrict__ ebm,
                  float* __restrict__ out)
{
    extern __shared__ float sm[];
    float* Ss = sm;
    float* G1 = sm + MT * SSP;
    float* G2 = G1 + MT * G1P;
    float* CF = G2 + MT * G1P;
    float* H1 = G1;           // overlays G1+G2 (dead by then)
    float* H2 = Ss;           // overlays Ss (dead by then)

    const int  t    = threadIdx.x;
    const int  lane = t & 63;
    const int  wv   = __builtin_amdgcn_readfirstlane(t >> 6);   // 0..7, wave-uniform
    const long srow0 = (long)blockIdx.x * MT;

    // ---- stage states tile (coalesced float4 from HBM) ----
    {
        const float4* src = reinterpret_cast<const float4*>(states + srow0 * NI);
        for (int q = t; q < MT * (NI / 4); q += T) {
            const int r  = q / (NI / 4);
            const int c4 = q - r * (NI / 4);
            const float4 v = src[q];
            float* d = &Ss[r * SSP + c4 * 4];
            d[0] = v.x; d[1] = v.y; d[2] = v.z; d[3] = v.w;
        }
    }
    __syncthreads();

    // ---- A1: g1 = relu(states @ bw1.T + bb1)   (N=128, K=376) ----
    {
        float acc[16];
        #pragma unroll
        for (int j = 0; j < 16; ++j) acc[j] = 0.f;
        const int c0 = wv * 16;
        const float* srow = &Ss[lane * SSP];
        for (int k = 0; k < NI; k += 4) {
            const float a0 = srow[k], a1 = srow[k+1], a2 = srow[k+2], a3 = srow[k+3];
            #pragma unroll
            for (int j = 0; j < 16; ++j) {
                const float4 w = *reinterpret_cast<const float4*>(&bw1[(c0 + j) * NI + k]);
                acc[j] = fmaf(a3, w.w, fmaf(a2, w.z, fmaf(a1, w.y, fmaf(a0, w.x, acc[j]))));
            }
        }
        #pragma unroll
        for (int j = 0; j < 16; ++j)
            G1[lane * G1P + c0 + j] = fmaxf(acc[j] + bb1[c0 + j], 0.f);
    }
    __syncthreads();

    // ---- A2: g2 = relu(g1 @ bw2.T + bb2)   (N=128, K=128) ----
    {
        float acc[16];
        #pragma unroll
        for (int j = 0; j < 16; ++j) acc[j] = 0.f;
        const int c0 = wv * 16;
        const float* grow = &G1[lane * G1P];
        for (int k = 0; k < 128; k += 4) {
            const float a0 = grow[k], a1 = grow[k+1], a2 = grow[k+2], a3 = grow[k+3];
            #pragma unroll
            for (int j = 0; j < 16; ++j) {
                const float4 w = *reinterpret_cast<const float4*>(&bw2[(c0 + j) * 128 + k]);
                acc[j] = fmaf(a3, w.w, fmaf(a2, w.z, fmaf(a1, w.y, fmaf(a0, w.x, acc[j]))));
            }
        }
        #pragma unroll
        for (int j = 0; j < 16; ++j)
            G2[lane * G1P + c0 + j] = fmaxf(acc[j] + bb2[c0 + j], 0.f);
    }
    __syncthreads();

    // ---- A3: coeffs = softmax(g2 @ bwo.T + bbo)  (2 experts) ----
    if (t < 128) {
        const int s = t >> 1, e = t & 1;
        const float* g = &G2[s * G1P];
        const float* w = bwo + e * 128;
        float z = bbo[e];
        for (int k = 0; k < 128; ++k) z = fmaf(g[k], w[k], z);
        CF[s * 2 + e] = z;
    }
    __syncthreads();
    if (t < 64) {
        const float z0 = CF[t * 2], z1 = CF[t * 2 + 1];
        const float m  = fmaxf(z0, z1);
        const float e0 = __expf(z0 - m), e1 = __expf(z1 - m);
        const float inv = 1.f / (e0 + e1);
        CF[t * 2]     = e0 * inv;
        CF[t * 2 + 1] = e1 * inv;
    }
    __syncthreads();

    // ---- B: h1 = relu(blend_e(states @ ew1[e].T + eb1[e]))  (N=256x2, K=376) ----
    {
        float accA[32], accB[32];
        #pragma unroll
        for (int j = 0; j < 32; ++j) { accA[j] = 0.f; accB[j] = 0.f; }
        const int o0 = wv * 32;
        const float* srow = &Ss[lane * SSP];
        for (int k = 0; k < NI; k += 4) {
            const float a0 = srow[k], a1 = srow[k+1], a2 = srow[k+2], a3 = srow[k+3];
            #pragma unroll
            for (int j = 0; j < 32; ++j) {
                const float4 w0 = *reinterpret_cast<const float4*>(&ew1[(o0 + j) * NI + k]);
                const float4 w1 = *reinterpret_cast<const float4*>(&ew1[(256 + o0 + j) * NI + k]);
                accA[j] = fmaf(a3, w0.w, fmaf(a2, w0.z, fmaf(a1, w0.y, fmaf(a0, w0.x, accA[j]))));
                accB[j] = fmaf(a3, w1.w, fmaf(a2, w1.z, fmaf(a1, w1.y, fmaf(a0, w1.x, accB[j]))));
            }
        }
        const float cc0 = CF[lane * 2], cc1 = CF[lane * 2 + 1];
        #pragma unroll
        for (int j = 0; j < 32; ++j) {
            const float v = cc0 * (accA[j] + eb1[o0 + j]) + cc1 * (accB[j] + eb1[256 + o0 + j]);
            H1[lane * H1P + o0 + j] = fmaxf(v, 0.f);
        }
    }
    __syncthreads();

    // ---- C: h2 = relu(blend_e(h1 @ ew2[e].T + eb2[e]))  (N=128x2, K=256) ----
    {
        float accA[16], accB[16];
        #pragma unroll
        for (int j = 0; j < 16; ++j) { accA[j] = 0.f; accB[j] = 0.f; }
        const int o0 = wv * 16;
        const float* hrow = &H1[lane * H1P];
        for (int k = 0; k < 256; k += 4) {
            const float a0 = hrow[k], a1 = hrow[k+1], a2 = hrow[k+2], a3 = hrow[k+3];
            #pragma unroll
            for (int j = 0; j < 16; ++j) {
                const float4 w0 = *reinterpret_cast<const float4*>(&ew2[(o0 + j) * 256 + k]);
                const float4 w1 = *reinterpret_cast<const float4*>(&ew2[(128 + o0 + j) * 256 + k]);
                accA[j] = fmaf(a3, w0.w, fmaf(a2, w0.z, fmaf(a1, w0.y, fmaf(a0, w0.x, accA[j]))));
                accB[j] = fmaf(a3, w1.w, fmaf(a2, w1.z, fmaf(a1, w1.y, fmaf(a0, w1.x, accB[j]))));
            }
        }
        const float cc0 = CF[lane * 2], cc1 = CF[lane * 2 + 1];
        #pragma unroll
        for (int j = 0; j < 16; ++j) {
            const float v = cc0 * (accA[j] + eb2[o0 + j]) + cc1 * (accB[j] + eb2[128 + o0 + j]);
            H2[lane * H2P + o0 + j] = fmaxf(v, 0.f);
        }
    }
    __syncthreads();

    // ---- D: mu = tanh(blend_e(h2 @ ewm[e].T + ebm[e]))  (N=17x2, K=128) ----
    for (int idx = t; idx < MT * 17; idx += T) {
        const int s = idx / 17;
        const int a = idx - s * 17;
        const float cc0 = CF[s * 2], cc1 = CF[s * 2 + 1];
        const float* h  = &H2[s * H2P];
        const float* w0 = ewm + a * 128;
        const float* w1 = ewm + (17 + a) * 128;
        float d0 = 0.f, d1 = 0.f;
        for (int k = 0; k < 128; ++k) {
            const float hv = h[k];
            d0 = fmaf(hv, w0[k], d0);
            d1 = fmaf(hv, w1[k], d1);
        }
        const float v = cc0 * (d0 + ebm[a]) + cc1 * (d1 + ebm[17 + a]);
        out[(srow0 + s) * 17 + a] = tanhf(v);
    }
}

extern "C" void kernel_launch(void* const* d_in, const int* in_sizes, int n_in,
                              void* d_out, int out_size, void* d_ws, size_t ws_size,
                              hipStream_t stream) {
    (void)in_sizes; (void)n_in; (void)d_ws; (void)ws_size; (void)out_size;
    const float* states = (const float*)d_in[0];
    const float* bw1 = (const float*)d_in[1];
    const float* bb1 = (const float*)d_in[2];
    const float* bw2 = (const float*)d_in[3];
    const float* bb2 = (const float*)d_in[4];
    const float* bwo = (const float*)d_in[5];
    const float* bbo = (const float*)d_in[6];
    const float* ew1 = (const float*)d_in[7];
    const float* eb1 = (const float*)d_in[8];
    const float* ew2 = (const float*)d_in[9];
    const float* eb2 = (const float*)d_in[10];
    const float* ewm = (const float*)d_in[11];
    const float* ebm = (const float*)d_in[12];
    float* out = (float*)d_out;

    const int nblk = 65536 / MT;            // 1024
    const size_t lds_bytes = LDS_FLOATS * sizeof(float);   // 163,072 B
    actor_kernel<<<dim3(nblk), dim3(T), lds_bytes, stream>>>(
        states, bw1, bb1, bw2, bb2, bwo, bbo,
        ew1, eb1, ew2, eb2, ewm, ebm, out);
}

// Round 2
// 2531.900 us; speedup vs baseline: 1.0326x; 1.0326x over previous
//
#include <hip/hip_runtime.h>
#include <math.h>

// Fused Actor network, fp32, spill-fixed.
// B=65536, NI=376, blending 376->128->128->2(softmax), experts 376->256->128->17 (blended, tanh)
// One block = 64 samples, 512 threads = 8 waves.
// lane (0..63) = sample row, wave (0..7) = output column group -> weight loads wave-uniform.
// Key fixes vs r1: amdgpu_waves_per_eu(2,2) (LDS pins 1 block/CU anyway -> let
// the allocator use VGPRs), and <=32 live accumulators per thread (no spills).

#define NI   376
#define MT   64
#define T    512
#define SSP  377   // states LDS row stride (odd -> 2-way max on 32 banks = free)
#define G1P  129
#define H1P  257
#define H2P  129

// LDS float layout:
//  Ss  [0, 24128)            : states [64][377]   (live: load..phase B)
//  G1  [24128, 32384)        : g1 [64][129]       (live: A1..A2)
//  G2  [32384, 40640)        : g2 [64][129]       (live: A2..A3)
//  CF  [40640, 40768)        : coeffs [64][2]     (live: A3..D)
//  H1 = [24128, 40576)       : h1 [64][257]       (overlays G1+G2, live: B..C)
//  H2 = [0, 8256)            : h2 [64][129]       (overlays Ss,    live: C..D)
#define LDS_FLOATS 40768

__global__ __launch_bounds__(512)
__attribute__((amdgpu_waves_per_eu(2, 2)))
void actor_kernel(const float* __restrict__ states,
                  const float* __restrict__ bw1, const float* __restrict__ bb1,
                  const float* __restrict__ bw2, const float* __restrict__ bb2,
                  const float* __restrict__ bwo, const float* __restrict__ bbo,
                  const float* __restrict__ ew1, const float* __restrict__ eb1,
                  const float* __restrict__ ew2, const float* __restrict__ eb2,
                  const float* __restrict__ ewm, const float* __restrict__ ebm,
                  float* __restrict__ out)
{
    extern __shared__ float sm[];
    float* Ss = sm;
    float* G1 = sm + MT * SSP;
    float* G2 = G1 + MT * G1P;
    float* CF = G2 + MT * G1P;
    float* H1 = G1;           // overlays G1+G2 (dead by then)
    float* H2 = Ss;           // overlays Ss (dead by then)

    const int  t    = threadIdx.x;
    const int  lane = t & 63;
    const int  wv   = __builtin_amdgcn_readfirstlane(t >> 6);   // 0..7, wave-uniform
    const long srow0 = (long)blockIdx.x * MT;

    // ---- stage states tile (coalesced float4 from HBM) ----
    {
        const float4* src = reinterpret_cast<const float4*>(states + srow0 * NI);
        for (int q = t; q < MT * (NI / 4); q += T) {
            const int r  = q / (NI / 4);
            const int c4 = q - r * (NI / 4);
            const float4 v = src[q];
            float* d = &Ss[r * SSP + c4 * 4];
            d[0] = v.x; d[1] = v.y; d[2] = v.z; d[3] = v.w;
        }
    }
    __syncthreads();

    // ---- A1: g1 = relu(states @ bw1.T + bb1)   (N=128, K=376) ----
    {
        float acc[16];
        #pragma unroll
        for (int j = 0; j < 16; ++j) acc[j] = 0.f;
        const int c0 = wv * 16;
        const float* srow = &Ss[lane * SSP];
        for (int k = 0; k < NI; k += 4) {
            const float a0 = srow[k], a1 = srow[k+1], a2 = srow[k+2], a3 = srow[k+3];
            #pragma unroll
            for (int j = 0; j < 16; ++j) {
                const float4 w = *reinterpret_cast<const float4*>(&bw1[(c0 + j) * NI + k]);
                acc[j] = fmaf(a3, w.w, fmaf(a2, w.z, fmaf(a1, w.y, fmaf(a0, w.x, acc[j]))));
            }
        }
        #pragma unroll
        for (int j = 0; j < 16; ++j)
            G1[lane * G1P + c0 + j] = fmaxf(acc[j] + bb1[c0 + j], 0.f);
    }
    __syncthreads();

    // ---- A2: g2 = relu(g1 @ bw2.T + bb2)   (N=128, K=128) ----
    {
        float acc[16];
        #pragma unroll
        for (int j = 0; j < 16; ++j) acc[j] = 0.f;
        const int c0 = wv * 16;
        const float* grow = &G1[lane * G1P];
        for (int k = 0; k < 128; k += 4) {
            const float a0 = grow[k], a1 = grow[k+1], a2 = grow[k+2], a3 = grow[k+3];
            #pragma unroll
            for (int j = 0; j < 16; ++j) {
                const float4 w = *reinterpret_cast<const float4*>(&bw2[(c0 + j) * 128 + k]);
                acc[j] = fmaf(a3, w.w, fmaf(a2, w.z, fmaf(a1, w.y, fmaf(a0, w.x, acc[j]))));
            }
        }
        #pragma unroll
        for (int j = 0; j < 16; ++j)
            G2[lane * G1P + c0 + j] = fmaxf(acc[j] + bb2[c0 + j], 0.f);
    }
    __syncthreads();

    // ---- A3: coeffs = softmax(g2 @ bwo.T + bbo)  (2 experts) ----
    if (t < 128) {
        const int s = t >> 1, e = t & 1;
        const float* g = &G2[s * G1P];
        const float* w = bwo + e * 128;
        float z = bbo[e];
        for (int k = 0; k < 128; ++k) z = fmaf(g[k], w[k], z);
        CF[s * 2 + e] = z;
    }
    __syncthreads();
    if (t < 64) {
        const float z0 = CF[t * 2], z1 = CF[t * 2 + 1];
        const float m  = fmaxf(z0, z1);
        const float e0 = __expf(z0 - m), e1 = __expf(z1 - m);
        const float inv = 1.f / (e0 + e1);
        CF[t * 2]     = e0 * inv;
        CF[t * 2 + 1] = e1 * inv;
    }
    __syncthreads();

    // ---- B: h1 = relu(blend_e(states @ ew1[e].T + eb1[e]))  (N=256x2, K=376) ----
    // 32 cols/wave per expert; two chunks of 16 so only 32 accumulators live.
    {
        const float cc0 = CF[lane * 2], cc1 = CF[lane * 2 + 1];
        #pragma unroll
        for (int half = 0; half < 2; ++half) {
            const int c0 = wv * 32 + half * 16;
            float accA[16], accB[16];
            #pragma unroll
            for (int j = 0; j < 16; ++j) { accA[j] = 0.f; accB[j] = 0.f; }
            const float* srow = &Ss[lane * SSP];
            for (int k = 0; k < NI; k += 4) {
                const float a0 = srow[k], a1 = srow[k+1], a2 = srow[k+2], a3 = srow[k+3];
                #pragma unroll
                for (int j = 0; j < 16; ++j) {
                    const float4 w0 = *reinterpret_cast<const float4*>(&ew1[(c0 + j) * NI + k]);
                    const float4 w1 = *reinterpret_cast<const float4*>(&ew1[(256 + c0 + j) * NI + k]);
                    accA[j] = fmaf(a3, w0.w, fmaf(a2, w0.z, fmaf(a1, w0.y, fmaf(a0, w0.x, accA[j]))));
                    accB[j] = fmaf(a3, w1.w, fmaf(a2, w1.z, fmaf(a1, w1.y, fmaf(a0, w1.x, accB[j]))));
                }
            }
            #pragma unroll
            for (int j = 0; j < 16; ++j) {
                const float v = cc0 * (accA[j] + eb1[c0 + j]) + cc1 * (accB[j] + eb1[256 + c0 + j]);
                H1[lane * H1P + c0 + j] = fmaxf(v, 0.f);
            }
        }
    }
    __syncthreads();

    // ---- C: h2 = relu(blend_e(h1 @ ew2[e].T + eb2[e]))  (N=128x2, K=256) ----
    {
        float accA[16], accB[16];
        #pragma unroll
        for (int j = 0; j < 16; ++j) { accA[j] = 0.f; accB[j] = 0.f; }
        const int o0 = wv * 16;
        const float* hrow = &H1[lane * H1P];
        for (int k = 0; k < 256; k += 4) {
            const float a0 = hrow[k], a1 = hrow[k+1], a2 = hrow[k+2], a3 = hrow[k+3];
            #pragma unroll
            for (int j = 0; j < 16; ++j) {
                const float4 w0 = *reinterpret_cast<const float4*>(&ew2[(o0 + j) * 256 + k]);
                const float4 w1 = *reinterpret_cast<const float4*>(&ew2[(128 + o0 + j) * 256 + k]);
                accA[j] = fmaf(a3, w0.w, fmaf(a2, w0.z, fmaf(a1, w0.y, fmaf(a0, w0.x, accA[j]))));
                accB[j] = fmaf(a3, w1.w, fmaf(a2, w1.z, fmaf(a1, w1.y, fmaf(a0, w1.x, accB[j]))));
            }
        }
        const float cc0 = CF[lane * 2], cc1 = CF[lane * 2 + 1];
        #pragma unroll
        for (int j = 0; j < 16; ++j) {
            const float v = cc0 * (accA[j] + eb2[o0 + j]) + cc1 * (accB[j] + eb2[128 + o0 + j]);
            H2[lane * H2P + o0 + j] = fmaxf(v, 0.f);
        }
    }
    __syncthreads();

    // ---- D: mu = tanh(blend_e(h2 @ ewm[e].T + ebm[e]))  (N=17x2, K=128) ----
    for (int idx = t; idx < MT * 17; idx += T) {
        const int s = idx / 17;
        const int a = idx - s * 17;
        const float cc0 = CF[s * 2], cc1 = CF[s * 2 + 1];
        const float* h  = &H2[s * H2P];
        const float* w0 = ewm + a * 128;
        const float* w1 = ewm + (17 + a) * 128;
        float d0 = 0.f, d1 = 0.f;
        for (int k = 0; k < 128; k += 4) {
            const float4 wv0 = *reinterpret_cast<const float4*>(&w0[k]);
            const float4 wv1 = *reinterpret_cast<const float4*>(&w1[k]);
            const float h0 = h[k], h1v = h[k+1], h2v = h[k+2], h3 = h[k+3];
            d0 = fmaf(h3, wv0.w, fmaf(h2v, wv0.z, fmaf(h1v, wv0.y, fmaf(h0, wv0.x, d0))));
            d1 = fmaf(h3, wv1.w, fmaf(h2v, wv1.z, fmaf(h1v, wv1.y, fmaf(h0, wv1.x, d1))));
        }
        const float v = cc0 * (d0 + ebm[a]) + cc1 * (d1 + ebm[17 + a]);
        out[(srow0 + s) * 17 + a] = tanhf(v);
    }
}

extern "C" void kernel_launch(void* const* d_in, const int* in_sizes, int n_in,
                              void* d_out, int out_size, void* d_ws, size_t ws_size,
                              hipStream_t stream) {
    (void)in_sizes; (void)n_in; (void)d_ws; (void)ws_size; (void)out_size;
    const float* states = (const float*)d_in[0];
    const float* bw1 = (const float*)d_in[1];
    const float* bb1 = (const float*)d_in[2];
    const float* bw2 = (const float*)d_in[3];
    const float* bb2 = (const float*)d_in[4];
    const float* bwo = (const float*)d_in[5];
    const float* bbo = (const float*)d_in[6];
    const float* ew1 = (const float*)d_in[7];
    const float* eb1 = (const float*)d_in[8];
    const float* ew2 = (const float*)d_in[9];
    const float* eb2 = (const float*)d_in[10];
    const float* ewm = (const float*)d_in[11];
    const float* ebm = (const float*)d_in[12];
    float* out = (float*)d_out;

    const int nblk = 65536 / MT;            // 1024
    const size_t lds_bytes = LDS_FLOATS * sizeof(float);   // 163,072 B
    actor_kernel<<<dim3(nblk), dim3(T), lds_bytes, stream>>>(
        states, bw1, bb1, bw2, bb2, bwo, bbo,
        ew1, eb1, ew2, eb2, ewm, ebm, out);
}

// Round 4
// 213.432 us; speedup vs baseline: 12.2491x; 11.8628x over previous
//
#include <hip/hip_runtime.h>
#include <math.h>

// Fused Actor network via split-precision bf16 MFMA (3-term Markidis per GEMM).
// Round 4: NO d_ws usage (weights split fp32->hi/lo bf16 on the fly, in-register);
// coeffs stored as bf16 pair in the S_lo K-pad (finite values x exactly-zero
// weight groups -> contribute exactly 0). Everything else identical to r3.
// Block = 64 samples, 512 threads = 8 waves. MFMA 16x16x32 bf16.

typedef __attribute__((ext_vector_type(8))) short  bf16x8;
typedef __attribute__((ext_vector_type(4))) float  f32x4;

#define MFMA16(a, b, c) __builtin_amdgcn_mfma_f32_16x16x32_bf16((a), (b), (c), 0, 0, 0)
#define SWZ(row) (((row) & 7) << 4)

// ---- LDS byte offsets (total exactly 163840 = 160 KiB) ----
// S_hi [0,49152): 64 rows x 384 bf16 (stride 768B). S_lo [49152,98304).
//   cols 376..383 zero-padded; S_lo pad bytes 752..756 hold (c0,c1) as bf16 after A3.
// G1 hi/lo, G2 hi/lo: 64x128 bf16 (stride 256B) in [98304,163840).
// H1 hi/lo overlays G1+G2: 64x256 bf16 (stride 512B).
// H2 hi/lo overlays S_hi: 64x128 bf16 (stride 256B).
#define S_HI_B   0
#define S_LO_B   49152
#define G1HI_B   98304
#define G1LO_B   114688
#define G2HI_B   131072
#define G2LO_B   147456
#define H1HI_B   98304
#define H1LO_B   131072
#define H2HI_B   0
#define H2LO_B   16384
#define LDS_BYTES 163840

__device__ __forceinline__ unsigned short bf16_rne(float x) {
    unsigned u = __builtin_bit_cast(unsigned, x);
    return (unsigned short)((u + 0x7FFFu + ((u >> 16) & 1u)) >> 16);
}
__device__ __forceinline__ float bf16_tof(unsigned short h) {
    return __builtin_bit_cast(float, ((unsigned)h) << 16);
}
__device__ __forceinline__ void split2(float x, unsigned short& h, unsigned short& l) {
    h = bf16_rne(x);
    l = bf16_rne(x - bf16_tof(h));
}
// load 8 consecutive fp32 weights at p, split to (bh,bl) bf16 fragments
__device__ __forceinline__ void load_split8(const float* __restrict__ p, bf16x8& bh, bf16x8& bl) {
    const float4 a = *reinterpret_cast<const float4*>(p);
    const float4 b = *reinterpret_cast<const float4*>(p + 4);
    unsigned short h, l;
    split2(a.x, h, l); bh[0] = (short)h; bl[0] = (short)l;
    split2(a.y, h, l); bh[1] = (short)h; bl[1] = (short)l;
    split2(a.z, h, l); bh[2] = (short)h; bl[2] = (short)l;
    split2(a.w, h, l); bh[3] = (short)h; bl[3] = (short)l;
    split2(b.x, h, l); bh[4] = (short)h; bl[4] = (short)l;
    split2(b.y, h, l); bh[5] = (short)h; bl[5] = (short)l;
    split2(b.z, h, l); bh[6] = (short)h; bl[6] = (short)l;
    split2(b.w, h, l); bh[7] = (short)h; bl[7] = (short)l;
}

__global__ __launch_bounds__(512)
__attribute__((amdgpu_waves_per_eu(2, 2)))
void actor_kernel(const float* __restrict__ states,
                  const float* __restrict__ bw1, const float* __restrict__ bb1,
                  const float* __restrict__ bw2, const float* __restrict__ bb2,
                  const float* __restrict__ bwo, const float* __restrict__ bbo,
                  const float* __restrict__ ew1, const float* __restrict__ eb1,
                  const float* __restrict__ ew2, const float* __restrict__ eb2,
                  const float* __restrict__ ewm, const float* __restrict__ ebm,
                  float* __restrict__ out)
{
    extern __shared__ char smc[];
    const int t    = threadIdx.x;
    const int l    = t & 63;
    const int l15  = l & 15;
    const int kgrp = l >> 4;          // 0..3: which 8-elem k-subgroup this lane owns
    const int kg16 = kgrp * 16;       // byte offset within a 32-col (64B) chunk
    const int wv   = __builtin_amdgcn_readfirstlane(t >> 6);
    const int base = blockIdx.x * 64;

    const bf16x8 zf = {0,0,0,0,0,0,0,0};

    // ---------- stage: states fp32 -> hi/lo bf16 in LDS (swizzled) ----------
    {
        const float4* src = reinterpret_cast<const float4*>(states + (long)base * 376);
        for (int q = t; q < 64 * 94; q += 512) {
            const int r  = q / 94;
            const int c4 = q - r * 94;
            const float4 v = src[q];
            unsigned short h0,h1,h2,h3,l0,l1,l2,l3;
            split2(v.x, h0, l0); split2(v.y, h1, l1); split2(v.z, h2, l2); split2(v.w, h3, l3);
            const int off = (r * 768 + c4 * 8) ^ SWZ(r);
            *(ushort4*)(smc + S_HI_B + off) = make_ushort4(h0, h1, h2, h3);
            *(ushort4*)(smc + S_LO_B + off) = make_ushort4(l0, l1, l2, l3);
        }
        if (t < 64) {  // zero K-pad cols 376..383 (bytes 752..768) of both arrays
            const int off = (t * 768 + 752) ^ SWZ(t);
            *(float4*)(smc + S_HI_B + off) = make_float4(0.f, 0.f, 0.f, 0.f);
            *(float4*)(smc + S_LO_B + off) = make_float4(0.f, 0.f, 0.f, 0.f);
        }
    }
    __syncthreads();

    // ---------- A1: G1 = relu(S @ bw1^T + bb1)  M=64 N=128 K=376(->384) ----------
    {
        f32x4 acc[4] = {{0,0,0,0},{0,0,0,0},{0,0,0,0},{0,0,0,0}};
        const int col = wv * 16 + l15;
        for (int kc = 0; kc < 12; ++kc) {
            const int g = kc * 4 + kgrp;          // 8-elem group; valid if g<47 (376/8)
            bf16x8 bh = zf, bl = zf;
            if (g < 47) load_split8(bw1 + col * 376 + g * 8, bh, bl);
            const int koff = kc * 64 + kg16;
            #pragma unroll
            for (int mt = 0; mt < 4; ++mt) {
                const int row = mt * 16 + l15;
                const int aoff = (row * 768 + koff) ^ SWZ(row);
                const bf16x8 ah = *(const bf16x8*)(smc + S_HI_B + aoff);
                const bf16x8 al = *(const bf16x8*)(smc + S_LO_B + aoff);
                acc[mt] = MFMA16(ah, bh, acc[mt]);
                acc[mt] = MFMA16(al, bh, acc[mt]);
                acc[mt] = MFMA16(ah, bl, acc[mt]);
            }
        }
        const float bias = bb1[col];
        #pragma unroll
        for (int mt = 0; mt < 4; ++mt) {
            #pragma unroll
            for (int j = 0; j < 4; ++j) {
                const int row = mt * 16 + kgrp * 4 + j;
                const float v = fmaxf(acc[mt][j] + bias, 0.f);
                unsigned short h, lo_; split2(v, h, lo_);
                const int off = (row * 256 + col * 2) ^ SWZ(row);
                *(unsigned short*)(smc + G1HI_B + off) = h;
                *(unsigned short*)(smc + G1LO_B + off) = lo_;
            }
        }
    }
    __syncthreads();

    // ---------- A2: G2 = relu(G1 @ bw2^T + bb2)  M=64 N=128 K=128 ----------
    {
        f32x4 acc[4] = {{0,0,0,0},{0,0,0,0},{0,0,0,0},{0,0,0,0}};
        const int col = wv * 16 + l15;
        for (int kc = 0; kc < 4; ++kc) {
            const int g = kc * 4 + kgrp;
            bf16x8 bh, bl;
            load_split8(bw2 + col * 128 + g * 8, bh, bl);
            const int koff = kc * 64 + kg16;
            #pragma unroll
            for (int mt = 0; mt < 4; ++mt) {
                const int row = mt * 16 + l15;
                const int aoff = (row * 256 + koff) ^ SWZ(row);
                const bf16x8 ah = *(const bf16x8*)(smc + G1HI_B + aoff);
                const bf16x8 al = *(const bf16x8*)(smc + G1LO_B + aoff);
                acc[mt] = MFMA16(ah, bh, acc[mt]);
                acc[mt] = MFMA16(al, bh, acc[mt]);
                acc[mt] = MFMA16(ah, bl, acc[mt]);
            }
        }
        const float bias = bb2[col];
        #pragma unroll
        for (int mt = 0; mt < 4; ++mt) {
            #pragma unroll
            for (int j = 0; j < 4; ++j) {
                const int row = mt * 16 + kgrp * 4 + j;
                const float v = fmaxf(acc[mt][j] + bias, 0.f);
                unsigned short h, lo_; split2(v, h, lo_);
                const int off = (row * 256 + col * 2) ^ SWZ(row);
                *(unsigned short*)(smc + G2HI_B + off) = h;
                *(unsigned short*)(smc + G2LO_B + off) = lo_;
            }
        }
    }
    __syncthreads();

    // ---------- A3: softmax coeffs -> (c0,c1) as bf16 in S_lo K-pad ----------
    if (t < 64) {
        float z0 = bbo[0], z1 = bbo[1];
        for (int k8 = 0; k8 < 16; ++k8) {
            const int off = (t * 256 + k8 * 16) ^ SWZ(t);
            const bf16x8 hv = *(const bf16x8*)(smc + G2HI_B + off);
            const bf16x8 lv = *(const bf16x8*)(smc + G2LO_B + off);
            #pragma unroll
            for (int j = 0; j < 8; ++j) {
                const float g = bf16_tof((unsigned short)hv[j]) + bf16_tof((unsigned short)lv[j]);
                z0 = fmaf(g, bwo[k8 * 8 + j], z0);
                z1 = fmaf(g, bwo[128 + k8 * 8 + j], z1);
            }
        }
        const float m  = fmaxf(z0, z1);
        const float e0 = __expf(z0 - m), e1 = __expf(z1 - m);
        const float inv = 1.f / (e0 + e1);
        const unsigned short c0h = bf16_rne(e0 * inv);
        const unsigned short c1h = bf16_rne(e1 * inv);
        // finite bf16 values; they multiply exactly-zero weight groups in E1 -> contribute 0
        *(ushort4*)(smc + S_LO_B + ((t * 768 + 752) ^ SWZ(t))) = make_ushort4(c0h, c1h, 0, 0);
    }
    __syncthreads();

    // ---------- E1: H1 = relu(blend(S @ ew1[e]^T + eb1[e]))  M=64 N=256x2 K=376(->384) ----------
    {
        f32x4 aA[2][4], aB[2][4];
        #pragma unroll
        for (int nt = 0; nt < 2; ++nt)
            #pragma unroll
            for (int mt = 0; mt < 4; ++mt) { aA[nt][mt] = {0,0,0,0}; aB[nt][mt] = {0,0,0,0}; }

        for (int kc = 0; kc < 12; ++kc) {
            const int g = kc * 4 + kgrp;
            const bool vg = (g < 47);
            const int koff = kc * 64 + kg16;
            bf16x8 ah[4], al[4];
            #pragma unroll
            for (int mt = 0; mt < 4; ++mt) {
                const int row = mt * 16 + l15;
                const int aoff = (row * 768 + koff) ^ SWZ(row);
                ah[mt] = *(const bf16x8*)(smc + S_HI_B + aoff);
                al[mt] = *(const bf16x8*)(smc + S_LO_B + aoff);
            }
            #pragma unroll
            for (int nt = 0; nt < 2; ++nt) {
                const int wr = wv * 32 + nt * 16 + l15;     // expert-0 weight row (= out col)
                bf16x8 bh0 = zf, bl0 = zf, bh1 = zf, bl1 = zf;
                if (vg) {
                    load_split8(ew1 + wr * 376 + g * 8,           bh0, bl0);
                    load_split8(ew1 + (wr + 256) * 376 + g * 8,   bh1, bl1);
                }
                #pragma unroll
                for (int mt = 0; mt < 4; ++mt) {
                    aA[nt][mt] = MFMA16(ah[mt], bh0, aA[nt][mt]);
                    aA[nt][mt] = MFMA16(al[mt], bh0, aA[nt][mt]);
                    aA[nt][mt] = MFMA16(ah[mt], bl0, aA[nt][mt]);
                    aB[nt][mt] = MFMA16(ah[mt], bh1, aB[nt][mt]);
                    aB[nt][mt] = MFMA16(al[mt], bh1, aB[nt][mt]);
                    aB[nt][mt] = MFMA16(ah[mt], bl1, aB[nt][mt]);
                }
            }
        }
        #pragma unroll
        for (int nt = 0; nt < 2; ++nt) {
            const int col = wv * 32 + nt * 16 + l15;
            const float b0 = eb1[col], b1 = eb1[256 + col];
            #pragma unroll
            for (int mt = 0; mt < 4; ++mt) {
                #pragma unroll
                for (int j = 0; j < 4; ++j) {
                    const int row = mt * 16 + kgrp * 4 + j;
                    const ushort2 cc = *(const ushort2*)(smc + S_LO_B + ((row * 768 + 752) ^ SWZ(row)));
                    const float c0 = bf16_tof(cc.x), c1 = bf16_tof(cc.y);
                    float v = c0 * (aA[nt][mt][j] + b0) + c1 * (aB[nt][mt][j] + b1);
                    v = fmaxf(v, 0.f);
                    unsigned short h, lo_; split2(v, h, lo_);
                    const int off = (row * 512 + col * 2) ^ SWZ(row);
                    *(unsigned short*)(smc + H1HI_B + off) = h;
                    *(unsigned short*)(smc + H1LO_B + off) = lo_;
                }
            }
        }
    }
    __syncthreads();

    // ---------- E2: H2 = relu(blend(H1 @ ew2[e]^T + eb2[e]))  M=64 N=128x2 K=256 ----------
    {
        f32x4 cA[4], cB[4];
        #pragma unroll
        for (int mt = 0; mt < 4; ++mt) { cA[mt] = {0,0,0,0}; cB[mt] = {0,0,0,0}; }
        const int col = wv * 16 + l15;
        for (int kc = 0; kc < 8; ++kc) {
            const int g = kc * 4 + kgrp;
            bf16x8 bh0, bl0, bh1, bl1;
            load_split8(ew2 + col * 256 + g * 8,           bh0, bl0);
            load_split8(ew2 + (col + 128) * 256 + g * 8,   bh1, bl1);
            const int koff = kc * 64 + kg16;
            #pragma unroll
            for (int mt = 0; mt < 4; ++mt) {
                const int row = mt * 16 + l15;
                const int aoff = (row * 512 + koff) ^ SWZ(row);
                const bf16x8 ah = *(const bf16x8*)(smc + H1HI_B + aoff);
                const bf16x8 al = *(const bf16x8*)(smc + H1LO_B + aoff);
                cA[mt] = MFMA16(ah, bh0, cA[mt]);
                cA[mt] = MFMA16(al, bh0, cA[mt]);
                cA[mt] = MFMA16(ah, bl0, cA[mt]);
                cB[mt] = MFMA16(ah, bh1, cB[mt]);
                cB[mt] = MFMA16(al, bh1, cB[mt]);
                cB[mt] = MFMA16(ah, bl1, cB[mt]);
            }
        }
        const float b0 = eb2[col], b1 = eb2[128 + col];
        #pragma unroll
        for (int mt = 0; mt < 4; ++mt) {
            #pragma unroll
            for (int j = 0; j < 4; ++j) {
                const int row = mt * 16 + kgrp * 4 + j;
                const ushort2 cc = *(const ushort2*)(smc + S_LO_B + ((row * 768 + 752) ^ SWZ(row)));
                const float c0 = bf16_tof(cc.x), c1 = bf16_tof(cc.y);
                float v = c0 * (cA[mt][j] + b0) + c1 * (cB[mt][j] + b1);
                v = fmaxf(v, 0.f);
                unsigned short h, lo_; split2(v, h, lo_);
                const int off = (row * 256 + col * 2) ^ SWZ(row);
                *(unsigned short*)(smc + H2HI_B + off) = h;
                *(unsigned short*)(smc + H2LO_B + off) = lo_;
            }
        }
    }
    __syncthreads();

    // ---------- E3: mu = tanh(blend(H2 @ ewm[e]^T + ebm[e]))  M=64 N=17x2 K=128 ----------
    {
        const int nt = wv & 1;        // col tile (2 x 16 covers 17 outputs)
        const int mt = wv >> 1;       // row tile
        f32x4 c0a = {0,0,0,0}, c1a = {0,0,0,0};
        const int col = nt * 16 + l15;
        const bool vcol = (col < 17);
        const int arow = mt * 16 + l15;
        for (int kc = 0; kc < 4; ++kc) {
            const int g = kc * 4 + kgrp;
            const int koff = kc * 64 + kg16;
            const int aoff = (arow * 256 + koff) ^ SWZ(arow);
            const bf16x8 ah = *(const bf16x8*)(smc + H2HI_B + aoff);
            const bf16x8 al = *(const bf16x8*)(smc + H2LO_B + aoff);
            bf16x8 bh0 = zf, bl0 = zf, bh1 = zf, bl1 = zf;
            if (vcol) {
                load_split8(ewm + col * 128 + g * 8,          bh0, bl0);
                load_split8(ewm + (17 + col) * 128 + g * 8,   bh1, bl1);
            }
            c0a = MFMA16(ah, bh0, c0a);
            c0a = MFMA16(al, bh0, c0a);
            c0a = MFMA16(ah, bl0, c0a);
            c1a = MFMA16(ah, bh1, c1a);
            c1a = MFMA16(al, bh1, c1a);
            c1a = MFMA16(ah, bl1, c1a);
        }
        if (vcol) {
            const float b0 = ebm[col], b1 = ebm[17 + col];
            #pragma unroll
            for (int j = 0; j < 4; ++j) {
                const int row = mt * 16 + kgrp * 4 + j;
                const ushort2 cc = *(const ushort2*)(smc + S_LO_B + ((row * 768 + 752) ^ SWZ(row)));
                const float c0 = bf16_tof(cc.x), c1 = bf16_tof(cc.y);
                const float v = c0 * (c0a[j] + b0) + c1 * (c1a[j] + b1);
                out[(long)(base + row) * 17 + col] = tanhf(v);
            }
        }
    }
}

extern "C" void kernel_launch(void* const* d_in, const int* in_sizes, int n_in,
                              void* d_out, int out_size, void* d_ws, size_t ws_size,
                              hipStream_t stream) {
    (void)in_sizes; (void)n_in; (void)out_size; (void)d_ws; (void)ws_size;
    const float* states = (const float*)d_in[0];
    const float* bw1 = (const float*)d_in[1];
    const float* bb1 = (const float*)d_in[2];
    const float* bw2 = (const float*)d_in[3];
    const float* bb2 = (const float*)d_in[4];
    const float* bwo = (const float*)d_in[5];
    const float* bbo = (const float*)d_in[6];
    const float* ew1 = (const float*)d_in[7];
    const float* eb1 = (const float*)d_in[8];
    const float* ew2 = (const float*)d_in[9];
    const float* eb2 = (const float*)d_in[10];
    const float* ewm = (const float*)d_in[11];
    const float* ebm = (const float*)d_in[12];
    float* out = (float*)d_out;

    actor_kernel<<<dim3(1024), dim3(512), LDS_BYTES, stream>>>(
        states, bw1, bb1, bw2, bb2, bwo, bbo,
        ew1, eb1, ew2, eb2, ewm, ebm, out);
}

// Round 5
// 132.702 us; speedup vs baseline: 19.7009x; 1.6084x over previous
//
#include <hip/hip_runtime.h>
#include <math.h>

// Fused Actor network via single-term fp16 MFMA.
// B=65536, blending 376->128->128->2(softmax), experts 376->256->128->17 blended, tanh.
// Block = 64 samples, 512 threads = 8 waves. MFMA 16x16x32 f16.
// Weights converted fp32->fp16 once into d_ws (if ws_size suffices), else on-the-fly cvt.
// LDS tiles XOR-swizzled: byte ^= (row&7)<<4. 80 KiB LDS -> 2 blocks/CU possible.

typedef __attribute__((ext_vector_type(8))) _Float16 half8;
typedef __attribute__((ext_vector_type(4))) _Float16 half4;
typedef __attribute__((ext_vector_type(4))) float    f32x4;

#define MFMA16(a, b, c) __builtin_amdgcn_mfma_f32_16x16x32_f16((a), (b), (c), 0, 0, 0)
#define SWZ(row) (((row) & 7) << 4)

// ---- LDS byte offsets (total 81,920 B) ----
// S  [0, 49152): 64 rows x 384 f16 (stride 768B). cols 376..383 zero-padded;
//    after A3, pad bytes 752..759 of each row hold (c0h,c0l,c1h,c1l) fp16.
//    (finite values x exactly-zero weight k-groups -> contribute exactly 0; live till E3)
// G1 [49152, 65536): 64x128 f16 (stride 256B)   (A1 out, A2 in)
// G2 [65536, 81920): 64x128 f16                 (A2 out, A3 in)
// H1 [49152, 81920): 64x256 f16 (stride 512B), overlays G1+G2 (E1 out, E2 in)
// H2 [49152, 65536): 64x128 f16, overlays H1 LOW half -> E2 needs barrier between
//    compute (reads H1) and epilogue write (writes H2).
#define S_B      0
#define G1_B     49152
#define G2_B     65536
#define H1_B     49152
#define H2_B     49152
#define LDS_BYTES 81920

// ---- ws fp16-element offsets (prep output; 335,872 halfs = 671,744 B) ----
#define WS_W1 0        /* bw1 padded: 128x384 */
#define WS_W2 49152    /* bw2: 128x128 */
#define WS_E1 65536    /* ew1 padded: 512x384 */
#define WS_E2 262144   /* ew2: 256x256 */
#define WS_EM 327680   /* ewm padded: 64x128 (2 experts x 32 rows, rows>=17 zero) */
#define WS_HALFS 335872
#define WS_BYTES 671744

__device__ __forceinline__ half8 cvt8(const float* __restrict__ p) {
    const float4 a = *reinterpret_cast<const float4*>(p);
    const float4 b = *reinterpret_cast<const float4*>(p + 4);
    half8 r;
    r[0] = (_Float16)a.x; r[1] = (_Float16)a.y; r[2] = (_Float16)a.z; r[3] = (_Float16)a.w;
    r[4] = (_Float16)b.x; r[5] = (_Float16)b.y; r[6] = (_Float16)b.z; r[7] = (_Float16)b.w;
    return r;
}

// ================= prep kernel: fp32 weights -> fp16 in ws, zero-padded =================
__global__ __launch_bounds__(256)
void prep_weights(const float* __restrict__ bw1, const float* __restrict__ bw2,
                  const float* __restrict__ ew1, const float* __restrict__ ew2,
                  const float* __restrict__ ewm, _Float16* __restrict__ wsw)
{
    const int i = blockIdx.x * 256 + threadIdx.x;
    float v; int idx;
    if (i < 49152) {                        // bw1: 128 x 384 (src K=376)
        const int o = i / 384, k = i - o * 384;
        v = (k < 376) ? bw1[o * 376 + k] : 0.f;
        idx = WS_W1 + i;
    } else if (i < 65536) {                 // bw2: 128 x 128
        const int j = i - 49152;
        v = bw2[j];
        idx = WS_W2 + j;
    } else if (i < 262144) {                // ew1: 512 x 384 (src 512 x 376)
        const int j = i - 65536;
        const int o = j / 384, k = j - o * 384;
        v = (k < 376) ? ew1[o * 376 + k] : 0.f;
        idx = WS_E1 + j;
    } else if (i < 327680) {                // ew2: 256 x 256
        const int j = i - 262144;
        v = ew2[j];
        idx = WS_E2 + j;
    } else if (i < WS_HALFS) {              // ewm: 64 x 128 (valid rows a<17 per expert)
        const int j = i - 327680;
        const int o = j / 128, k = j - o * 128;
        const int e = o >> 5, a = o & 31;
        v = (a < 17) ? ewm[(e * 17 + a) * 128 + k] : 0.f;
        idx = WS_EM + j;
    } else return;
    wsw[idx] = (_Float16)v;
}

// ================= fused actor kernel =================
template <bool USE_WS>
__global__ __launch_bounds__(512)
__attribute__((amdgpu_waves_per_eu(2)))
void actor_kernel(const float* __restrict__ states,
                  const float* __restrict__ bw1, const float* __restrict__ bb1,
                  const float* __restrict__ bw2, const float* __restrict__ bb2,
                  const float* __restrict__ bwo, const float* __restrict__ bbo,
                  const float* __restrict__ ew1, const float* __restrict__ eb1,
                  const float* __restrict__ ew2, const float* __restrict__ eb2,
                  const float* __restrict__ ewm, const float* __restrict__ ebm,
                  const _Float16* __restrict__ wsw,
                  float* __restrict__ out)
{
    extern __shared__ char smc[];
    const int t    = threadIdx.x;
    const int l    = t & 63;
    const int l15  = l & 15;
    const int kgrp = l >> 4;          // 0..3: which 8-elem k-subgroup this lane owns
    const int kg16 = kgrp * 16;       // byte offset within a 32-col (64B) chunk
    const int wv   = __builtin_amdgcn_readfirstlane(t >> 6);
    const int base = blockIdx.x * 64;

    const half8 zf = {0,0,0,0,0,0,0,0};

    // ---------- stage: states fp32 -> fp16 in LDS (swizzled) ----------
    {
        const float4* src = reinterpret_cast<const float4*>(states + (long)base * 376);
        for (int q = t; q < 64 * 94; q += 512) {
            const int r  = q / 94;
            const int c4 = q - r * 94;
            const float4 v = src[q];
            half4 h;
            h[0] = (_Float16)v.x; h[1] = (_Float16)v.y;
            h[2] = (_Float16)v.z; h[3] = (_Float16)v.w;
            *(half4*)(smc + S_B + ((r * 768 + c4 * 8) ^ SWZ(r))) = h;
        }
        if (t < 64) {  // zero K-pad cols 376..383 (bytes 752..768)
            *(float4*)(smc + S_B + ((t * 768 + 752) ^ SWZ(t))) = make_float4(0.f, 0.f, 0.f, 0.f);
        }
    }
    __syncthreads();

    // ---------- A1: G1 = relu(S @ bw1^T + bb1)  M=64 N=128 K=376(->384) ----------
    {
        f32x4 acc[4] = {{0,0,0,0},{0,0,0,0},{0,0,0,0},{0,0,0,0}};
        const int col = wv * 16 + l15;
        for (int kc = 0; kc < 12; ++kc) {
            const int g = kc * 4 + kgrp;          // 8-elem k-group; src valid if g<47
            half8 bf;
            if constexpr (USE_WS) bf = *(const half8*)(wsw + WS_W1 + col * 384 + g * 8);
            else                  bf = (g < 47) ? cvt8(bw1 + col * 376 + g * 8) : zf;
            const int koff = kc * 64 + kg16;
            #pragma unroll
            for (int mt = 0; mt < 4; ++mt) {
                const int row = mt * 16 + l15;
                const half8 af = *(const half8*)(smc + S_B + ((row * 768 + koff) ^ SWZ(row)));
                acc[mt] = MFMA16(af, bf, acc[mt]);
            }
        }
        const float bias = bb1[col];
        #pragma unroll
        for (int mt = 0; mt < 4; ++mt) {
            #pragma unroll
            for (int j = 0; j < 4; ++j) {
                const int row = mt * 16 + kgrp * 4 + j;
                const float v = fmaxf(acc[mt][j] + bias, 0.f);
                *(_Float16*)(smc + G1_B + ((row * 256 + col * 2) ^ SWZ(row))) = (_Float16)v;
            }
        }
    }
    __syncthreads();

    // ---------- A2: G2 = relu(G1 @ bw2^T + bb2)  M=64 N=128 K=128 ----------
    {
        f32x4 acc[4] = {{0,0,0,0},{0,0,0,0},{0,0,0,0},{0,0,0,0}};
        const int col = wv * 16 + l15;
        for (int kc = 0; kc < 4; ++kc) {
            const int g = kc * 4 + kgrp;
            half8 bf;
            if constexpr (USE_WS) bf = *(const half8*)(wsw + WS_W2 + col * 128 + g * 8);
            else                  bf = cvt8(bw2 + col * 128 + g * 8);
            const int koff = kc * 64 + kg16;
            #pragma unroll
            for (int mt = 0; mt < 4; ++mt) {
                const int row = mt * 16 + l15;
                const half8 af = *(const half8*)(smc + G1_B + ((row * 256 + koff) ^ SWZ(row)));
                acc[mt] = MFMA16(af, bf, acc[mt]);
            }
        }
        const float bias = bb2[col];
        #pragma unroll
        for (int mt = 0; mt < 4; ++mt) {
            #pragma unroll
            for (int j = 0; j < 4; ++j) {
                const int row = mt * 16 + kgrp * 4 + j;
                const float v = fmaxf(acc[mt][j] + bias, 0.f);
                *(_Float16*)(smc + G2_B + ((row * 256 + col * 2) ^ SWZ(row))) = (_Float16)v;
            }
        }
    }
    __syncthreads();

    // ---------- A3: softmax coeffs -> (c0h,c0l,c1h,c1l) fp16 in S K-pad ----------
    if (t < 64) {
        float z0 = bbo[0], z1 = bbo[1];
        for (int k8 = 0; k8 < 16; ++k8) {
            const half8 hv = *(const half8*)(smc + G2_B + ((t * 256 + k8 * 16) ^ SWZ(t)));
            #pragma unroll
            for (int j = 0; j < 8; ++j) {
                const float g = (float)hv[j];
                z0 = fmaf(g, bwo[k8 * 8 + j], z0);
                z1 = fmaf(g, bwo[128 + k8 * 8 + j], z1);
            }
        }
        const float m  = fmaxf(z0, z1);
        const float e0 = __expf(z0 - m), e1 = __expf(z1 - m);
        const float inv = 1.f / (e0 + e1);
        const float c0 = e0 * inv, c1 = e1 * inv;
        half4 cc;
        cc[0] = (_Float16)c0; cc[1] = (_Float16)(c0 - (float)cc[0]);
        cc[2] = (_Float16)c1; cc[3] = (_Float16)(c1 - (float)cc[2]);
        // finite fp16 values in A-operand K-pad; matching weight k-groups are zero -> no effect
        *(half4*)(smc + S_B + ((t * 768 + 752) ^ SWZ(t))) = cc;
    }
    __syncthreads();

    // ---------- E1: H1 = relu(blend(S @ ew1[e]^T + eb1[e]))  M=64 N=256x2 K=376(->384) ----------
    {
        f32x4 aA[2][4], aB[2][4];
        #pragma unroll
        for (int nt = 0; nt < 2; ++nt)
            #pragma unroll
            for (int mt = 0; mt < 4; ++mt) { aA[nt][mt] = {0,0,0,0}; aB[nt][mt] = {0,0,0,0}; }

        for (int kc = 0; kc < 12; ++kc) {
            const int g = kc * 4 + kgrp;
            const bool vg = (g < 47);
            const int koff = kc * 64 + kg16;
            half8 af[4];
            #pragma unroll
            for (int mt = 0; mt < 4; ++mt) {
                const int row = mt * 16 + l15;
                af[mt] = *(const half8*)(smc + S_B + ((row * 768 + koff) ^ SWZ(row)));
            }
            #pragma unroll
            for (int nt = 0; nt < 2; ++nt) {
                const int wr = wv * 32 + nt * 16 + l15;     // expert-0 weight row (= out col)
                half8 b0, b1;
                if constexpr (USE_WS) {
                    b0 = *(const half8*)(wsw + WS_E1 + wr * 384 + g * 8);
                    b1 = *(const half8*)(wsw + WS_E1 + (wr + 256) * 384 + g * 8);
                } else {
                    b0 = vg ? cvt8(ew1 + wr * 376 + g * 8)         : zf;
                    b1 = vg ? cvt8(ew1 + (wr + 256) * 376 + g * 8) : zf;
                }
                #pragma unroll
                for (int mt = 0; mt < 4; ++mt) {
                    aA[nt][mt] = MFMA16(af[mt], b0, aA[nt][mt]);
                    aB[nt][mt] = MFMA16(af[mt], b1, aB[nt][mt]);
                }
            }
        }
        #pragma unroll
        for (int nt = 0; nt < 2; ++nt) {
            const int col = wv * 32 + nt * 16 + l15;
            const float b0 = eb1[col], b1 = eb1[256 + col];
            #pragma unroll
            for (int mt = 0; mt < 4; ++mt) {
                #pragma unroll
                for (int j = 0; j < 4; ++j) {
                    const int row = mt * 16 + kgrp * 4 + j;
                    const half4 cc = *(const half4*)(smc + S_B + ((row * 768 + 752) ^ SWZ(row)));
                    const float c0 = (float)cc[0] + (float)cc[1];
                    const float c1 = (float)cc[2] + (float)cc[3];
                    float v = c0 * (aA[nt][mt][j] + b0) + c1 * (aB[nt][mt][j] + b1);
                    v = fmaxf(v, 0.f);
                    *(_Float16*)(smc + H1_B + ((row * 512 + col * 2) ^ SWZ(row))) = (_Float16)v;
                }
            }
        }
    }
    __syncthreads();

    // ---------- E2: H2 = relu(blend(H1 @ ew2[e]^T + eb2[e]))  M=64 N=128x2 K=256 ----------
    {
        f32x4 cA[4], cB[4];
        #pragma unroll
        for (int mt = 0; mt < 4; ++mt) { cA[mt] = {0,0,0,0}; cB[mt] = {0,0,0,0}; }
        const int col = wv * 16 + l15;
        for (int kc = 0; kc < 8; ++kc) {
            const int g = kc * 4 + kgrp;
            half8 b0, b1;
            if constexpr (USE_WS) {
                b0 = *(const half8*)(wsw + WS_E2 + col * 256 + g * 8);
                b1 = *(const half8*)(wsw + WS_E2 + (col + 128) * 256 + g * 8);
            } else {
                b0 = cvt8(ew2 + col * 256 + g * 8);
                b1 = cvt8(ew2 + (col + 128) * 256 + g * 8);
            }
            const int koff = kc * 64 + kg16;
            #pragma unroll
            for (int mt = 0; mt < 4; ++mt) {
                const int row = mt * 16 + l15;
                const half8 af = *(const half8*)(smc + H1_B + ((row * 512 + koff) ^ SWZ(row)));
                cA[mt] = MFMA16(af, b0, cA[mt]);
                cB[mt] = MFMA16(af, b1, cB[mt]);
            }
        }
        __syncthreads();   // all H1 reads complete before H2 overlays H1's low half
        const float b0 = eb2[col], b1 = eb2[128 + col];
        #pragma unroll
        for (int mt = 0; mt < 4; ++mt) {
            #pragma unroll
            for (int j = 0; j < 4; ++j) {
                const int row = mt * 16 + kgrp * 4 + j;
                const half4 cc = *(const half4*)(smc + S_B + ((row * 768 + 752) ^ SWZ(row)));
                const float c0 = (float)cc[0] + (float)cc[1];
                const float c1 = (float)cc[2] + (float)cc[3];
                float v = c0 * (cA[mt][j] + b0) + c1 * (cB[mt][j] + b1);
                v = fmaxf(v, 0.f);
                *(_Float16*)(smc + H2_B + ((row * 256 + col * 2) ^ SWZ(row))) = (_Float16)v;
            }
        }
    }
    __syncthreads();

    // ---------- E3: mu = tanh(blend(H2 @ ewm[e]^T + ebm[e]))  M=64 N=17x2 K=128 ----------
    {
        const int nt = wv & 1;        // col tile (2 x 16 covers 17 outputs)
        const int mt = wv >> 1;       // row tile
        f32x4 c0a = {0,0,0,0}, c1a = {0,0,0,0};
        const int col = nt * 16 + l15;
        const bool vcol = (col < 17);
        const int arow = mt * 16 + l15;
        for (int kc = 0; kc < 4; ++kc) {
            const int g = kc * 4 + kgrp;
            const int koff = kc * 64 + kg16;
            const half8 af = *(const half8*)(smc + H2_B + ((arow * 256 + koff) ^ SWZ(arow)));
            half8 b0, b1;
            if constexpr (USE_WS) {
                b0 = *(const half8*)(wsw + WS_EM + col * 128 + g * 8);
                b1 = *(const half8*)(wsw + WS_EM + (col + 32) * 128 + g * 8);
            } else {
                b0 = vcol ? cvt8(ewm + col * 128 + g * 8)        : zf;
                b1 = vcol ? cvt8(ewm + (17 + col) * 128 + g * 8) : zf;
            }
            c0a = MFMA16(af, b0, c0a);
            c1a = MFMA16(af, b1, c1a);
        }
        if (vcol) {
            const float b0 = ebm[col], b1 = ebm[17 + col];
            #pragma unroll
            for (int j = 0; j < 4; ++j) {
                const int row = mt * 16 + kgrp * 4 + j;
                const half4 cc = *(const half4*)(smc + S_B + ((row * 768 + 752) ^ SWZ(row)));
                const float c0 = (float)cc[0] + (float)cc[1];
                const float c1 = (float)cc[2] + (float)cc[3];
                const float v = c0 * (c0a[j] + b0) + c1 * (c1a[j] + b1);
                out[(long)(base + row) * 17 + col] = tanhf(v);
            }
        }
    }
}

extern "C" void kernel_launch(void* const* d_in, const int* in_sizes, int n_in,
                              void* d_out, int out_size, void* d_ws, size_t ws_size,
                              hipStream_t stream) {
    (void)in_sizes; (void)n_in; (void)out_size;
    const float* states = (const float*)d_in[0];
    const float* bw1 = (const float*)d_in[1];
    const float* bb1 = (const float*)d_in[2];
    const float* bw2 = (const float*)d_in[3];
    const float* bb2 = (const float*)d_in[4];
    const float* bwo = (const float*)d_in[5];
    const float* bbo = (const float*)d_in[6];
    const float* ew1 = (const float*)d_in[7];
    const float* eb1 = (const float*)d_in[8];
    const float* ew2 = (const float*)d_in[9];
    const float* eb2 = (const float*)d_in[10];
    const float* ewm = (const float*)d_in[11];
    const float* ebm = (const float*)d_in[12];
    float* out = (float*)d_out;

    if (d_ws != nullptr && ws_size >= (size_t)WS_BYTES) {
        _Float16* wsw = (_Float16*)d_ws;
        prep_weights<<<dim3(1312), dim3(256), 0, stream>>>(bw1, bw2, ew1, ew2, ewm, wsw);
        actor_kernel<true><<<dim3(1024), dim3(512), LDS_BYTES, stream>>>(
            states, bw1, bb1, bw2, bb2, bwo, bbo,
            ew1, eb1, ew2, eb2, ewm, ebm, wsw, out);
    } else {
        actor_kernel<false><<<dim3(1024), dim3(512), LDS_BYTES, stream>>>(
            states, bw1, bb1, bw2, bb2, bwo, bbo,
            ew1, eb1, ew2, eb2, ewm, ebm, nullptr, out);
    }
}

// Round 6
// 96.076 us; speedup vs baseline: 27.2113x; 1.3812x over previous
//
#include <hip/hip_runtime.h>
#include <math.h>

// Fused Actor network via single-term fp16 MFMA. Round 6: occupancy + coalesced weights.
// B=65536, blending 376->128->128->2(softmax), experts 376->256->128->17 blended, tanh.
// Block = 32 samples, 512 threads = 8 waves, LDS 40960 B -> 2 blocks/CU (16 waves, ~50%).
// Weights pre-tiled into d_ws as MFMA B-fragments: tile[n0][kc] = 16x32 f16, inner
// layout [lane][8] -> wave load = 64 consecutive 16B = 1KB coalesced burst.
// LDS XOR-swizzle: byte ^= (row&7)<<4 (row strides are multiples of 128B).

typedef __attribute__((ext_vector_type(8))) _Float16 half8;
typedef __attribute__((ext_vector_type(4))) _Float16 half4;
typedef __attribute__((ext_vector_type(4))) float    f32x4;

#define MFMA16(a, b, c) __builtin_amdgcn_mfma_f32_16x16x32_f16((a), (b), (c), 0, 0, 0)
#define SWZ(row) (((row) & 7) << 4)

#define MT 32
#define T  512

// ---- LDS byte offsets (total 40,960 B) ----
// S  [0, 24576): 32 rows x 384 f16 (stride 768B); cols 376..383 zero-padded;
//    after A3 pad bytes 752..759 hold (c0h,c0l,c1h,c1l) fp16 per row (x zero weights -> 0).
// G1 [24576, 32768): 32x128 f16 (stride 256B)
// G2 [32768, 40960): 32x128 f16
// H1 [24576, 40960): 32x256 f16 (stride 512B), overlays G1+G2
// H2 [24576, 32768): 32x128 f16, overlays H1 low half (barrier between read + write)
#define S_B      0
#define G1_B     24576
#define G2_B     32768
#define H1_B     24576
#define H2_B     24576
#define LDS_BYTES 40960

// ---- ws half-element offsets; tiled layout: tile(n0,kc) at ((n0*KC+kc)*512), [lane][8] ----
#define WS_W1 0        /* bw1: N0=8,  KC=12 -> 49152 halfs */
#define WS_W2 49152    /* bw2: N0=8,  KC=4  -> 16384 */
#define WS_E1 65536    /* ew1: N0=32, KC=12 -> 196608 */
#define WS_E2 262144   /* ew2: N0=16, KC=8  -> 65536 */
#define WS_EM 327680   /* ewm: N0=4,  KC=4  -> 8192 (2 experts x 32 rows padded) */
#define WS_HALFS 335872
#define WS_BYTES 671744

__device__ __forceinline__ half8 cvt8(const float* __restrict__ p) {
    const float4 a = *reinterpret_cast<const float4*>(p);
    const float4 b = *reinterpret_cast<const float4*>(p + 4);
    half8 r;
    r[0] = (_Float16)a.x; r[1] = (_Float16)a.y; r[2] = (_Float16)a.z; r[3] = (_Float16)a.w;
    r[4] = (_Float16)b.x; r[5] = (_Float16)b.y; r[6] = (_Float16)b.z; r[7] = (_Float16)b.w;
    return r;
}

// ================= prep kernel: fp32 weights -> fp16 B-fragment tiles in ws =================
// For a matrix W[N][K]: tile t = n0*KC + kc; within tile, half index = l*8 + j maps to
// n = n0*16 + (l&15), k = kc*32 + (l>>4)*8 + j. Out-of-range (n,k) -> 0.
__global__ __launch_bounds__(256)
void prep_weights(const float* __restrict__ bw1, const float* __restrict__ bw2,
                  const float* __restrict__ ew1, const float* __restrict__ ew2,
                  const float* __restrict__ ewm, _Float16* __restrict__ wsw)
{
    const int i = blockIdx.x * 256 + threadIdx.x;
    if (i >= WS_HALFS) return;
    const float* W; int N, K, KC, j0;
    if      (i < 49152)  { W = bw1; N = 128; K = 376; KC = 12; j0 = i - WS_W1; }
    else if (i < 65536)  { W = bw2; N = 128; K = 128; KC = 4;  j0 = i - WS_W2; }
    else if (i < 262144) { W = ew1; N = 512; K = 376; KC = 12; j0 = i - WS_E1; }
    else if (i < 327680) { W = ew2; N = 256; K = 256; KC = 8;  j0 = i - WS_E2; }
    else                 { W = ewm; N = 34;  K = 128; KC = 4;  j0 = i - WS_EM; }
    const int tile = j0 >> 9;
    const int rem  = j0 & 511;
    const int l    = rem >> 3;
    const int jj   = rem & 7;
    const int n0   = tile / KC, kc = tile - n0 * KC;
    int n = n0 * 16 + (l & 15);
    const int k = kc * 32 + (l >> 4) * 8 + jj;
    float v = 0.f;
    if (W == ewm) {  // ewm logical rows: 2 experts x 32 padded rows -> src 2 x 17
        const int e = n >> 5, a = n & 31;
        if (a < 17 && k < K) v = ewm[(e * 17 + a) * K + k];
    } else {
        if (n < N && k < K) v = W[n * K + k];
    }
    wsw[i] = (_Float16)v;
}

// ================= fused actor kernel =================
template <bool USE_WS>
__global__ __launch_bounds__(512)
__attribute__((amdgpu_waves_per_eu(4)))
void actor_kernel(const float* __restrict__ states,
                  const float* __restrict__ bw1, const float* __restrict__ bb1,
                  const float* __restrict__ bw2, const float* __restrict__ bb2,
                  const float* __restrict__ bwo, const float* __restrict__ bbo,
                  const float* __restrict__ ew1, const float* __restrict__ eb1,
                  const float* __restrict__ ew2, const float* __restrict__ eb2,
                  const float* __restrict__ ewm, const float* __restrict__ ebm,
                  const _Float16* __restrict__ wsw,
                  float* __restrict__ out)
{
    extern __shared__ char smc[];
    const int t    = threadIdx.x;
    const int l    = t & 63;
    const int l15  = l & 15;
    const int kgrp = l >> 4;          // 0..3
    const int kg16 = kgrp * 16;       // byte offset within a 32-col (64B) chunk
    const int wv   = __builtin_amdgcn_readfirstlane(t >> 6);
    const int base = blockIdx.x * MT;
    const int lB   = l * 8;           // half offset of this lane's frag within a ws tile

    const half8 zf = {0,0,0,0,0,0,0,0};

    // ---------- stage: states fp32 -> fp16 in LDS (swizzled) ----------
    {
        const float4* src = reinterpret_cast<const float4*>(states + (long)base * 376);
        for (int q = t; q < MT * 94; q += T) {
            const int r  = q / 94;
            const int c4 = q - r * 94;
            const float4 v = src[q];
            half4 h;
            h[0] = (_Float16)v.x; h[1] = (_Float16)v.y;
            h[2] = (_Float16)v.z; h[3] = (_Float16)v.w;
            *(half4*)(smc + S_B + ((r * 768 + c4 * 8) ^ SWZ(r))) = h;
        }
        if (t < MT) {  // zero K-pad cols 376..383 (bytes 752..768)
            *(float4*)(smc + S_B + ((t * 768 + 752) ^ SWZ(t))) = make_float4(0.f, 0.f, 0.f, 0.f);
        }
    }
    __syncthreads();

    // ---------- A1: G1 = relu(S @ bw1^T + bb1)  M=32 N=128 K=384 ----------
    {
        f32x4 acc[2] = {{0,0,0,0},{0,0,0,0}};
        const int col = wv * 16 + l15;
        for (int kc = 0; kc < 12; ++kc) {
            half8 bf;
            if constexpr (USE_WS) bf = *(const half8*)(wsw + WS_W1 + (wv * 12 + kc) * 512 + lB);
            else {
                const int g = kc * 4 + kgrp;
                bf = (g < 47) ? cvt8(bw1 + col * 376 + g * 8) : zf;
            }
            const int koff = kc * 64 + kg16;
            #pragma unroll
            for (int mt = 0; mt < 2; ++mt) {
                const int row = mt * 16 + l15;
                const half8 af = *(const half8*)(smc + S_B + ((row * 768 + koff) ^ SWZ(row)));
                acc[mt] = MFMA16(af, bf, acc[mt]);
            }
        }
        const float bias = bb1[col];
        #pragma unroll
        for (int mt = 0; mt < 2; ++mt) {
            #pragma unroll
            for (int j = 0; j < 4; ++j) {
                const int row = mt * 16 + kgrp * 4 + j;
                const float v = fmaxf(acc[mt][j] + bias, 0.f);
                *(_Float16*)(smc + G1_B + ((row * 256 + col * 2) ^ SWZ(row))) = (_Float16)v;
            }
        }
    }
    __syncthreads();

    // ---------- A2: G2 = relu(G1 @ bw2^T + bb2)  M=32 N=128 K=128 ----------
    {
        f32x4 acc[2] = {{0,0,0,0},{0,0,0,0}};
        const int col = wv * 16 + l15;
        for (int kc = 0; kc < 4; ++kc) {
            half8 bf;
            if constexpr (USE_WS) bf = *(const half8*)(wsw + WS_W2 + (wv * 4 + kc) * 512 + lB);
            else                  bf = cvt8(bw2 + col * 128 + (kc * 4 + kgrp) * 8);
            const int koff = kc * 64 + kg16;
            #pragma unroll
            for (int mt = 0; mt < 2; ++mt) {
                const int row = mt * 16 + l15;
                const half8 af = *(const half8*)(smc + G1_B + ((row * 256 + koff) ^ SWZ(row)));
                acc[mt] = MFMA16(af, bf, acc[mt]);
            }
        }
        const float bias = bb2[col];
        #pragma unroll
        for (int mt = 0; mt < 2; ++mt) {
            #pragma unroll
            for (int j = 0; j < 4; ++j) {
                const int row = mt * 16 + kgrp * 4 + j;
                const float v = fmaxf(acc[mt][j] + bias, 0.f);
                *(_Float16*)(smc + G2_B + ((row * 256 + col * 2) ^ SWZ(row))) = (_Float16)v;
            }
        }
    }
    __syncthreads();

    // ---------- A3: softmax coeffs -> (c0h,c0l,c1h,c1l) fp16 in S K-pad ----------
    if (t < MT) {
        float z0 = bbo[0], z1 = bbo[1];
        for (int k8 = 0; k8 < 16; ++k8) {
            const half8 hv = *(const half8*)(smc + G2_B + ((t * 256 + k8 * 16) ^ SWZ(t)));
            #pragma unroll
            for (int j = 0; j < 8; ++j) {
                const float g = (float)hv[j];
                z0 = fmaf(g, bwo[k8 * 8 + j], z0);
                z1 = fmaf(g, bwo[128 + k8 * 8 + j], z1);
            }
        }
        const float m  = fmaxf(z0, z1);
        const float e0 = __expf(z0 - m), e1 = __expf(z1 - m);
        const float inv = 1.f / (e0 + e1);
        const float c0 = e0 * inv, c1 = e1 * inv;
        half4 cc;
        cc[0] = (_Float16)c0; cc[1] = (_Float16)(c0 - (float)cc[0]);
        cc[2] = (_Float16)c1; cc[3] = (_Float16)(c1 - (float)cc[2]);
        *(half4*)(smc + S_B + ((t * 768 + 752) ^ SWZ(t))) = cc;
    }
    __syncthreads();

    // ---------- E1: H1 = relu(blend(S @ ew1[e]^T + eb1[e]))  M=32 N=256x2 K=384 ----------
    {
        f32x4 aA[2][2], aB[2][2];   // [nt][mt]
        #pragma unroll
        for (int nt = 0; nt < 2; ++nt)
            #pragma unroll
            for (int mt = 0; mt < 2; ++mt) { aA[nt][mt] = {0,0,0,0}; aB[nt][mt] = {0,0,0,0}; }

        for (int kc = 0; kc < 12; ++kc) {
            const int koff = kc * 64 + kg16;
            half8 af[2];
            #pragma unroll
            for (int mt = 0; mt < 2; ++mt) {
                const int row = mt * 16 + l15;
                af[mt] = *(const half8*)(smc + S_B + ((row * 768 + koff) ^ SWZ(row)));
            }
            #pragma unroll
            for (int nt = 0; nt < 2; ++nt) {
                half8 b0, b1;
                if constexpr (USE_WS) {
                    const int n0 = wv * 2 + nt;
                    b0 = *(const half8*)(wsw + WS_E1 + (n0 * 12 + kc) * 512 + lB);
                    b1 = *(const half8*)(wsw + WS_E1 + ((16 + n0) * 12 + kc) * 512 + lB);
                } else {
                    const int g = kc * 4 + kgrp;
                    const int wr = wv * 32 + nt * 16 + l15;
                    b0 = (g < 47) ? cvt8(ew1 + wr * 376 + g * 8)         : zf;
                    b1 = (g < 47) ? cvt8(ew1 + (wr + 256) * 376 + g * 8) : zf;
                }
                #pragma unroll
                for (int mt = 0; mt < 2; ++mt) {
                    aA[nt][mt] = MFMA16(af[mt], b0, aA[nt][mt]);
                    aB[nt][mt] = MFMA16(af[mt], b1, aB[nt][mt]);
                }
            }
        }
        #pragma unroll
        for (int nt = 0; nt < 2; ++nt) {
            const int col = wv * 32 + nt * 16 + l15;
            const float b0 = eb1[col], b1 = eb1[256 + col];
            #pragma unroll
            for (int mt = 0; mt < 2; ++mt) {
                #pragma unroll
                for (int j = 0; j < 4; ++j) {
                    const int row = mt * 16 + kgrp * 4 + j;
                    const half4 cc = *(const half4*)(smc + S_B + ((row * 768 + 752) ^ SWZ(row)));
                    const float c0 = (float)cc[0] + (float)cc[1];
                    const float c1 = (float)cc[2] + (float)cc[3];
                    float v = c0 * (aA[nt][mt][j] + b0) + c1 * (aB[nt][mt][j] + b1);
                    v = fmaxf(v, 0.f);
                    *(_Float16*)(smc + H1_B + ((row * 512 + col * 2) ^ SWZ(row))) = (_Float16)v;
                }
            }
        }
    }
    __syncthreads();

    // ---------- E2: H2 = relu(blend(H1 @ ew2[e]^T + eb2[e]))  M=32 N=128x2 K=256 ----------
    {
        f32x4 cA[2], cB[2];
        #pragma unroll
        for (int mt = 0; mt < 2; ++mt) { cA[mt] = {0,0,0,0}; cB[mt] = {0,0,0,0}; }
        const int col = wv * 16 + l15;
        for (int kc = 0; kc < 8; ++kc) {
            half8 b0, b1;
            if constexpr (USE_WS) {
                b0 = *(const half8*)(wsw + WS_E2 + (wv * 8 + kc) * 512 + lB);
                b1 = *(const half8*)(wsw + WS_E2 + ((8 + wv) * 8 + kc) * 512 + lB);
            } else {
                const int g = kc * 4 + kgrp;
                b0 = cvt8(ew2 + col * 256 + g * 8);
                b1 = cvt8(ew2 + (col + 128) * 256 + g * 8);
            }
            const int koff = kc * 64 + kg16;
            #pragma unroll
            for (int mt = 0; mt < 2; ++mt) {
                const int row = mt * 16 + l15;
                const half8 af = *(const half8*)(smc + H1_B + ((row * 512 + koff) ^ SWZ(row)));
                cA[mt] = MFMA16(af, b0, cA[mt]);
                cB[mt] = MFMA16(af, b1, cB[mt]);
            }
        }
        __syncthreads();   // all H1 reads done before H2 overlays H1 low half
        const float b0 = eb2[col], b1 = eb2[128 + col];
        #pragma unroll
        for (int mt = 0; mt < 2; ++mt) {
            #pragma unroll
            for (int j = 0; j < 4; ++j) {
                const int row = mt * 16 + kgrp * 4 + j;
                const half4 cc = *(const half4*)(smc + S_B + ((row * 768 + 752) ^ SWZ(row)));
                const float c0 = (float)cc[0] + (float)cc[1];
                const float c1 = (float)cc[2] + (float)cc[3];
                float v = c0 * (cA[mt][j] + b0) + c1 * (cB[mt][j] + b1);
                v = fmaxf(v, 0.f);
                *(_Float16*)(smc + H2_B + ((row * 256 + col * 2) ^ SWZ(row))) = (_Float16)v;
            }
        }
    }
    __syncthreads();

    // ---------- E3: mu = tanh(blend(H2 @ ewm[e]^T + ebm[e]))  M=32 N=17x2 K=128 ----------
    if (wv < 4) {
        const int colt = wv & 1;      // col tile (2x16 covers 17)
        const int mt   = wv >> 1;     // row tile
        f32x4 c0a = {0,0,0,0}, c1a = {0,0,0,0};
        const int col  = colt * 16 + l15;
        const bool vcol = (col < 17);
        const int arow = mt * 16 + l15;
        for (int kc = 0; kc < 4; ++kc) {
            const int koff = kc * 64 + kg16;
            const half8 af = *(const half8*)(smc + H2_B + ((arow * 256 + koff) ^ SWZ(arow)));
            half8 b0, b1;
            if constexpr (USE_WS) {
                b0 = *(const half8*)(wsw + WS_EM + (colt * 4 + kc) * 512 + lB);
                b1 = *(const half8*)(wsw + WS_EM + ((2 + colt) * 4 + kc) * 512 + lB);
            } else {
                const int g = kc * 4 + kgrp;
                b0 = vcol ? cvt8(ewm + col * 128 + g * 8)        : zf;
                b1 = vcol ? cvt8(ewm + (17 + col) * 128 + g * 8) : zf;
            }
            c0a = MFMA16(af, b0, c0a);
            c1a = MFMA16(af, b1, c1a);
        }
        if (vcol) {
            const float b0 = ebm[col], b1 = ebm[17 + col];
            #pragma unroll
            for (int j = 0; j < 4; ++j) {
                const int row = mt * 16 + kgrp * 4 + j;
                const half4 cc = *(const half4*)(smc + S_B + ((row * 768 + 752) ^ SWZ(row)));
                const float c0 = (float)cc[0] + (float)cc[1];
                const float c1 = (float)cc[2] + (float)cc[3];
                const float v = c0 * (c0a[j] + b0) + c1 * (c1a[j] + b1);
                out[(long)(base + row) * 17 + col] = tanhf(v);
            }
        }
    }
}

extern "C" void kernel_launch(void* const* d_in, const int* in_sizes, int n_in,
                              void* d_out, int out_size, void* d_ws, size_t ws_size,
                              hipStream_t stream) {
    (void)in_sizes; (void)n_in; (void)out_size;
    const float* states = (const float*)d_in[0];
    const float* bw1 = (const float*)d_in[1];
    const float* bb1 = (const float*)d_in[2];
    const float* bw2 = (const float*)d_in[3];
    const float* bb2 = (const float*)d_in[4];
    const float* bwo = (const float*)d_in[5];
    const float* bbo = (const float*)d_in[6];
    const float* ew1 = (const float*)d_in[7];
    const float* eb1 = (const float*)d_in[8];
    const float* ew2 = (const float*)d_in[9];
    const float* eb2 = (const float*)d_in[10];
    const float* ewm = (const float*)d_in[11];
    const float* ebm = (const float*)d_in[12];
    float* out = (float*)d_out;

    const int nblk = 65536 / MT;   // 2048

    if (d_ws != nullptr && ws_size >= (size_t)WS_BYTES) {
        _Float16* wsw = (_Float16*)d_ws;
        prep_weights<<<dim3((WS_HALFS + 255) / 256), dim3(256), 0, stream>>>(
            bw1, bw2, ew1, ew2, ewm, wsw);
        actor_kernel<true><<<dim3(nblk), dim3(T), LDS_BYTES, stream>>>(
            states, bw1, bb1, bw2, bb2, bwo, bbo,
            ew1, eb1, ew2, eb2, ewm, ebm, wsw, out);
    } else {
        actor_kernel<false><<<dim3(nblk), dim3(T), LDS_BYTES, stream>>>(
            states, bw1, bb1, bw2, bb2, bwo, bbo,
            ew1, eb1, ew2, eb2, ewm, ebm, nullptr, out);
    }
}